// Round 1
// baseline (194.357 us; speedup 1.0000x reference)
//
#include <hip/hip_runtime.h>

// GroupStratifiedSurvivalLoss: per-sample Weibull NLL + mean + 16 group means.
// Memory-bound streaming reduction: float4 loads, grid-stride, LDS group bins.

namespace {
constexpr int NG = 16;       // number of groups
constexpr int BLOCK = 256;   // threads per block (4 waves)
constexpr int NWAVES = BLOCK / 64;
}

__global__ __launch_bounds__(BLOCK) void gssl_main_kernel(
    const float* __restrict__ bptr,   // shape
    const float* __restrict__ aptr,   // scale
    const float* __restrict__ yptr,   // time
    const float* __restrict__ uptr,   // event
    const int*   __restrict__ gptr,   // group
    float* __restrict__ ws,           // ws[0..15]=gsum, ws[16..31]=gcnt
    int n4, int n)
{
    __shared__ float lsum[NWAVES][NG];
    __shared__ float lcnt[NWAVES][NG];
    const int tid = threadIdx.x;
    const int wv  = tid >> 6;

    for (int i = tid; i < NWAVES * NG; i += BLOCK) {
        (&lsum[0][0])[i] = 0.0f;
        (&lcnt[0][0])[i] = 0.0f;
    }
    __syncthreads();

    const int stride = gridDim.x * BLOCK;
    for (int i = blockIdx.x * BLOCK + tid; i < n4; i += stride) {
        const float4 b4 = reinterpret_cast<const float4*>(bptr)[i];
        const float4 a4 = reinterpret_cast<const float4*>(aptr)[i];
        const float4 y4 = reinterpret_cast<const float4*>(yptr)[i];
        const float4 u4 = reinterpret_cast<const float4*>(uptr)[i];
        const int4   g4 = reinterpret_cast<const int4*>(gptr)[i];
        const float bb[4] = {b4.x, b4.y, b4.z, b4.w};
        const float aa[4] = {a4.x, a4.y, a4.z, a4.w};
        const float yy[4] = {y4.x, y4.y, y4.z, y4.w};
        const float uu[4] = {u4.x, u4.y, u4.z, u4.w};
        const int   gg[4] = {g4.x, g4.y, g4.z, g4.w};
        #pragma unroll
        for (int k = 0; k < 4; ++k) {
            const float b = bb[k], a = aa[k], y = yy[k], u = uu[k];
            const float inva = 1.0f / a;
            // hazard0 = (y + 1e-35/a)^b == y^b in f32 (y >= 0.1, term ~1e-35)
            const float h1 = __powf(y + inva, b);
            const float h0 = __powf(y, b);
            // d = h1-h0 >= ~0.13 over the input ranges -> exp(d)-1 well away from 0
            const float t  = __logf(__expf(h1 - h0) - 1.0f);
            const float ps = h1 - u * t;   // -(u*t - h1)
            atomicAdd(&lsum[wv][gg[k]], ps);
            atomicAdd(&lcnt[wv][gg[k]], 1.0f);
        }
    }

    // Tail (n not divisible by 4) — N=2^24 so this is empty, kept for safety.
    if (blockIdx.x == 0 && tid == 0) {
        for (int i = n4 * 4; i < n; ++i) {
            const float b = bptr[i], a = aptr[i], y = yptr[i], u = uptr[i];
            const float inva = 1.0f / a;
            const float h1 = __powf(y + inva, b);
            const float h0 = __powf(y, b);
            const float t  = __logf(__expf(h1 - h0) - 1.0f);
            const float ps = h1 - u * t;
            atomicAdd(&ws[gptr[i]], ps);
            atomicAdd(&ws[NG + gptr[i]], 1.0f);
        }
    }

    __syncthreads();
    if (tid < NG) {
        float s = 0.0f, c = 0.0f;
        #pragma unroll
        for (int w = 0; w < NWAVES; ++w) { s += lsum[w][tid]; c += lcnt[w][tid]; }
        atomicAdd(&ws[tid], s);
        atomicAdd(&ws[NG + tid], c);
    }
}

__global__ __launch_bounds__(64) void gssl_final_kernel(
    const float* __restrict__ ws, float* __restrict__ out, float invN)
{
    const int t = threadIdx.x;
    if (t < NG) {
        const float gs = ws[t];
        const float gc = ws[NG + t];
        out[1 + t] = gs / fmaxf(gc, 1.0f);
    }
    // loss = (sum over groups of gsum) / N
    float v = (t < NG) ? ws[t] : 0.0f;
    #pragma unroll
    for (int off = 32; off > 0; off >>= 1) v += __shfl_down(v, off);
    if (t == 0) out[0] = v * invN;
}

extern "C" void kernel_launch(void* const* d_in, const int* in_sizes, int n_in,
                              void* d_out, int out_size, void* d_ws, size_t ws_size,
                              hipStream_t stream) {
    const float* shape_p = (const float*)d_in[0];
    const float* scale_p = (const float*)d_in[1];
    const float* time_p  = (const float*)d_in[2];
    const float* event_p = (const float*)d_in[3];
    // d_in[4] = lengths: only its length (== n) is used by the reference.
    const int*   group_p = (const int*)d_in[5];
    float* out = (float*)d_out;
    float* ws  = (float*)d_ws;

    const int n  = in_sizes[0];
    const int n4 = n >> 2;

    // ws is poisoned 0xAA and never re-poisoned between replays: zero it every call.
    hipMemsetAsync(ws, 0, 2 * NG * sizeof(float), stream);

    int blocks = 2048;
    const int need = (n4 + BLOCK - 1) / BLOCK;
    if (need < blocks) blocks = (need > 0) ? need : 1;

    hipLaunchKernelGGL(gssl_main_kernel, dim3(blocks), dim3(BLOCK), 0, stream,
                       shape_p, scale_p, time_p, event_p, group_p, ws, n4, n);
    hipLaunchKernelGGL(gssl_final_kernel, dim3(1), dim3(64), 0, stream,
                       ws, out, 1.0f / (float)n);
}

// Round 2
// 183.967 us; speedup vs baseline: 1.0565x; 1.0565x over previous
//
#include <hip/hip_runtime.h>

// GroupStratifiedSurvivalLoss: per-sample Weibull NLL + mean + 16 group means.
// R1: replace __ocml pow/exp/log calls with raw gfx950 transcendental
// instructions (v_log_f32 / v_exp_f32 / v_rcp_f32) — R0 was VALU-bound
// (81% VALUBusy, 10% HBM) on library powf.

namespace {
constexpr int NG = 16;       // number of groups
constexpr int BLOCK = 256;   // threads per block (4 waves)
constexpr int NWAVES = BLOCK / 64;
constexpr float LOG2E = 1.4426950408889634f;
constexpr float LN2   = 0.6931471805599453f;
}

__device__ __forceinline__ float flog2(float x) { return __builtin_amdgcn_logf(x); }
__device__ __forceinline__ float fexp2(float x) { return __builtin_amdgcn_exp2f(x); }
__device__ __forceinline__ float frcp(float x)  { return __builtin_amdgcn_rcpf(x); }

// per-sample NLL: h1 - u * log(exp(h1-h0) - 1), h1=(y+1/a)^b, h0=y^b
__device__ __forceinline__ float per_sample(float b, float a, float y, float u) {
    const float inva = frcp(a);
    const float h1 = fexp2(b * flog2(y + inva));
    const float h0 = fexp2(b * flog2(y));
    const float em1 = fexp2((h1 - h0) * LOG2E) - 1.0f;   // exp(d)-1, d >= ~0.13
    const float t = flog2(em1) * LN2;                     // log(exp(d)-1)
    return __builtin_fmaf(-u, t, h1);                     // h1 - u*t
}

__global__ __launch_bounds__(BLOCK) void gssl_main_kernel(
    const float* __restrict__ bptr,   // shape
    const float* __restrict__ aptr,   // scale
    const float* __restrict__ yptr,   // time
    const float* __restrict__ uptr,   // event
    const int*   __restrict__ gptr,   // group
    float* __restrict__ ws,           // ws[0..15]=gsum, ws[16..31]=gcnt
    int n4, int n)
{
    __shared__ float lsum[NWAVES][NG];
    __shared__ float lcnt[NWAVES][NG];
    const int tid = threadIdx.x;
    const int wv  = tid >> 6;

    for (int i = tid; i < NWAVES * NG; i += BLOCK) {
        (&lsum[0][0])[i] = 0.0f;
        (&lcnt[0][0])[i] = 0.0f;
    }
    __syncthreads();

    const int stride = gridDim.x * BLOCK;
    for (int i = blockIdx.x * BLOCK + tid; i < n4; i += stride) {
        const float4 b4 = reinterpret_cast<const float4*>(bptr)[i];
        const float4 a4 = reinterpret_cast<const float4*>(aptr)[i];
        const float4 y4 = reinterpret_cast<const float4*>(yptr)[i];
        const float4 u4 = reinterpret_cast<const float4*>(uptr)[i];
        const int4   g4 = reinterpret_cast<const int4*>(gptr)[i];
        const float bb[4] = {b4.x, b4.y, b4.z, b4.w};
        const float aa[4] = {a4.x, a4.y, a4.z, a4.w};
        const float yy[4] = {y4.x, y4.y, y4.z, y4.w};
        const float uu[4] = {u4.x, u4.y, u4.z, u4.w};
        const int   gg[4] = {g4.x, g4.y, g4.z, g4.w};
        #pragma unroll
        for (int k = 0; k < 4; ++k) {
            const float ps = per_sample(bb[k], aa[k], yy[k], uu[k]);
            atomicAdd(&lsum[wv][gg[k]], ps);
            atomicAdd(&lcnt[wv][gg[k]], 1.0f);
        }
    }

    // Tail (n not divisible by 4) — N=2^24 so this is empty, kept for safety.
    if (blockIdx.x == 0 && tid == 0) {
        for (int i = n4 * 4; i < n; ++i) {
            const float ps = per_sample(bptr[i], aptr[i], yptr[i], uptr[i]);
            atomicAdd(&ws[gptr[i]], ps);
            atomicAdd(&ws[NG + gptr[i]], 1.0f);
        }
    }

    __syncthreads();
    if (tid < NG) {
        float s = 0.0f, c = 0.0f;
        #pragma unroll
        for (int w = 0; w < NWAVES; ++w) { s += lsum[w][tid]; c += lcnt[w][tid]; }
        atomicAdd(&ws[tid], s);
        atomicAdd(&ws[NG + tid], c);
    }
}

__global__ __launch_bounds__(64) void gssl_final_kernel(
    const float* __restrict__ ws, float* __restrict__ out, float invN)
{
    const int t = threadIdx.x;
    if (t < NG) {
        const float gs = ws[t];
        const float gc = ws[NG + t];
        out[1 + t] = gs / fmaxf(gc, 1.0f);
    }
    // loss = (sum over groups of gsum) / N
    float v = (t < NG) ? ws[t] : 0.0f;
    #pragma unroll
    for (int off = 32; off > 0; off >>= 1) v += __shfl_down(v, off);
    if (t == 0) out[0] = v * invN;
}

extern "C" void kernel_launch(void* const* d_in, const int* in_sizes, int n_in,
                              void* d_out, int out_size, void* d_ws, size_t ws_size,
                              hipStream_t stream) {
    const float* shape_p = (const float*)d_in[0];
    const float* scale_p = (const float*)d_in[1];
    const float* time_p  = (const float*)d_in[2];
    const float* event_p = (const float*)d_in[3];
    // d_in[4] = lengths: only its length (== n) is used by the reference.
    const int*   group_p = (const int*)d_in[5];
    float* out = (float*)d_out;
    float* ws  = (float*)d_ws;

    const int n  = in_sizes[0];
    const int n4 = n >> 2;

    // ws is poisoned 0xAA and never re-poisoned between replays: zero it every call.
    hipMemsetAsync(ws, 0, 2 * NG * sizeof(float), stream);

    int blocks = 2048;
    const int need = (n4 + BLOCK - 1) / BLOCK;
    if (need < blocks) blocks = (need > 0) ? need : 1;

    hipLaunchKernelGGL(gssl_main_kernel, dim3(blocks), dim3(BLOCK), 0, stream,
                       shape_p, scale_p, time_p, event_p, group_p, ws, n4, n);
    hipLaunchKernelGGL(gssl_final_kernel, dim3(1), dim3(64), 0, stream,
                       ws, out, 1.0f / (float)n);
}

// Round 3
// 80.501 us; speedup vs baseline: 2.4143x; 2.2853x over previous
//
#include <hip/hip_runtime.h>

// GroupStratifiedSurvivalLoss: per-sample Weibull NLL + mean + 16 group means.
// R2: kill per-element LDS atomics (R1 showed all pipes idle -> DS-atomic
// serialization bound). Per-thread register bins (16 sum + 16 cnt), branchless
// compile-time-indexed select accumulate, wave butterfly reduce at the end.

namespace {
constexpr int NG = 16;       // number of groups
constexpr int BLOCK = 256;   // threads per block (4 waves)
constexpr float LOG2E = 1.4426950408889634f;
constexpr float LN2   = 0.6931471805599453f;
}

__device__ __forceinline__ float flog2(float x) { return __builtin_amdgcn_logf(x); }
__device__ __forceinline__ float fexp2(float x) { return __builtin_amdgcn_exp2f(x); }
__device__ __forceinline__ float frcp(float x)  { return __builtin_amdgcn_rcpf(x); }

// per-sample NLL: h1 - u * log(exp(h1-h0) - 1), h1=(y+1/a)^b, h0=y^b
__device__ __forceinline__ float per_sample(float b, float a, float y, float u) {
    const float inva = frcp(a);
    const float h1 = fexp2(b * flog2(y + inva));
    const float h0 = fexp2(b * flog2(y));
    const float em1 = fexp2((h1 - h0) * LOG2E) - 1.0f;   // exp(d)-1, d >= ~0.13
    const float t = flog2(em1) * LN2;                     // log(exp(d)-1)
    return __builtin_fmaf(-u, t, h1);                     // h1 - u*t
}

__global__ __launch_bounds__(BLOCK) void gssl_main_kernel(
    const float* __restrict__ bptr,   // shape
    const float* __restrict__ aptr,   // scale
    const float* __restrict__ yptr,   // time
    const float* __restrict__ uptr,   // event
    const int*   __restrict__ gptr,   // group
    float* __restrict__ ws,           // ws[0..15]=gsum, ws[16..31]=gcnt
    int n4, int n)
{
    __shared__ float sbin[2 * NG];
    const int tid = threadIdx.x;
    if (tid < 2 * NG) sbin[tid] = 0.0f;
    __syncthreads();

    // Per-thread register bins — ALL indices compile-time (full unroll).
    float asum[NG], acnt[NG];
    #pragma unroll
    for (int q = 0; q < NG; ++q) { asum[q] = 0.0f; acnt[q] = 0.0f; }

    const int stride = gridDim.x * BLOCK;
    for (int i = blockIdx.x * BLOCK + tid; i < n4; i += stride) {
        const float4 b4 = reinterpret_cast<const float4*>(bptr)[i];
        const float4 a4 = reinterpret_cast<const float4*>(aptr)[i];
        const float4 y4 = reinterpret_cast<const float4*>(yptr)[i];
        const float4 u4 = reinterpret_cast<const float4*>(uptr)[i];
        const int4   g4 = reinterpret_cast<const int4*>(gptr)[i];
        const float bb[4] = {b4.x, b4.y, b4.z, b4.w};
        const float aa[4] = {a4.x, a4.y, a4.z, a4.w};
        const float yy[4] = {y4.x, y4.y, y4.z, y4.w};
        const float uu[4] = {u4.x, u4.y, u4.z, u4.w};
        const int   gg[4] = {g4.x, g4.y, g4.z, g4.w};
        #pragma unroll
        for (int k = 0; k < 4; ++k) {
            const float ps = per_sample(bb[k], aa[k], yy[k], uu[k]);
            const int g = gg[k];
            #pragma unroll
            for (int q = 0; q < NG; ++q) {
                const float m = (g == q) ? 1.0f : 0.0f;
                asum[q] = __builtin_fmaf(m, ps, asum[q]);
                acnt[q] += m;
            }
        }
    }

    // Wave-level butterfly reduction: every lane ends with the wave total.
    #pragma unroll
    for (int q = 0; q < NG; ++q) {
        #pragma unroll
        for (int off = 32; off > 0; off >>= 1) {
            asum[q] += __shfl_xor(asum[q], off, 64);
            acnt[q] += __shfl_xor(acnt[q], off, 64);
        }
    }

    // One lane per wave folds into block bins (4 waves x 32 LDS atomics).
    if ((tid & 63) == 0) {
        #pragma unroll
        for (int q = 0; q < NG; ++q) {
            atomicAdd(&sbin[q], asum[q]);
            atomicAdd(&sbin[NG + q], acnt[q]);
        }
    }
    __syncthreads();

    // Block -> global: 32 atomics per block.
    if (tid < 2 * NG) atomicAdd(&ws[tid], sbin[tid]);

    // Tail (n not divisible by 4) — N=2^24 so this is empty, kept for safety.
    if (blockIdx.x == 0 && tid == 0) {
        for (int i = n4 * 4; i < n; ++i) {
            const float ps = per_sample(bptr[i], aptr[i], yptr[i], uptr[i]);
            atomicAdd(&ws[gptr[i]], ps);
            atomicAdd(&ws[NG + gptr[i]], 1.0f);
        }
    }
}

__global__ __launch_bounds__(64) void gssl_final_kernel(
    const float* __restrict__ ws, float* __restrict__ out, float invN)
{
    const int t = threadIdx.x;
    if (t < NG) {
        const float gs = ws[t];
        const float gc = ws[NG + t];
        out[1 + t] = gs / fmaxf(gc, 1.0f);
    }
    // loss = (sum over groups of gsum) / N
    float v = (t < NG) ? ws[t] : 0.0f;
    #pragma unroll
    for (int off = 32; off > 0; off >>= 1) v += __shfl_down(v, off);
    if (t == 0) out[0] = v * invN;
}

extern "C" void kernel_launch(void* const* d_in, const int* in_sizes, int n_in,
                              void* d_out, int out_size, void* d_ws, size_t ws_size,
                              hipStream_t stream) {
    const float* shape_p = (const float*)d_in[0];
    const float* scale_p = (const float*)d_in[1];
    const float* time_p  = (const float*)d_in[2];
    const float* event_p = (const float*)d_in[3];
    // d_in[4] = lengths: only its length (== n) is used by the reference.
    const int*   group_p = (const int*)d_in[5];
    float* out = (float*)d_out;
    float* ws  = (float*)d_ws;

    const int n  = in_sizes[0];
    const int n4 = n >> 2;

    // ws is poisoned 0xAA and never re-poisoned between replays: zero it every call.
    hipMemsetAsync(ws, 0, 2 * NG * sizeof(float), stream);

    int blocks = 2048;
    const int need = (n4 + BLOCK - 1) / BLOCK;
    if (need < blocks) blocks = (need > 0) ? need : 1;

    hipLaunchKernelGGL(gssl_main_kernel, dim3(blocks), dim3(BLOCK), 0, stream,
                       shape_p, scale_p, time_p, event_p, group_p, ws, n4, n);
    hipLaunchKernelGGL(gssl_final_kernel, dim3(1), dim3(64), 0, stream,
                       ws, out, 1.0f / (float)n);
}